// Round 1
// baseline (444.828 us; speedup 1.0000x reference)
//
#include <hip/hip_runtime.h>
#include <math.h>

// Problem constants (fixed shapes from setup_inputs)
constexpr int TOPK = 8;
constexpr int NUM_SPECIAL = 999;
constexpr int V = 30522;
constexpr int D = 768;
constexpr int BLOCK = 256;
constexpr int NCAND = BLOCK * TOPK;   // 2048 candidate keys in LDS

// Monotone map float -> uint32 (order-preserving), packed with ~idx so that
// larger key == (larger value, then SMALLER index)  -- matches jax.lax.top_k
// tie-breaking (lower index first among equal values).
__device__ __forceinline__ unsigned long long fkey(float v, unsigned int idx) {
    unsigned int u = __float_as_uint(v);
    u = ((int)u < 0) ? ~u : (u | 0x80000000u);
    return ((unsigned long long)u << 32) | (unsigned long long)(~idx);
}

__device__ __forceinline__ void ins8(unsigned long long (&loc)[TOPK],
                                     unsigned long long key) {
    if (key > loc[TOPK - 1]) {
        loc[TOPK - 1] = key;
        // one bubble pass percolates the new element into place (list sorted desc)
        #pragma unroll
        for (int j = TOPK - 1; j > 0; --j) {
            unsigned long long a = loc[j - 1], b = loc[j];
            loc[j - 1] = a > b ? a : b;
            loc[j]     = a > b ? b : a;
        }
    }
}

__global__ __launch_bounds__(BLOCK) void dvat_kernel(
    const float* __restrict__ delta_grad,   // [B,S,D]
    const float* __restrict__ src_embeds,   // [B,S,D]
    const float* __restrict__ emb,          // [V,D]
    const int*   __restrict__ src_tokens,   // [B,S]
    const float* __restrict__ pred_lm,      // [B,S,V]
    const int*   __restrict__ attn,         // [B,S]
    const float* __restrict__ rand_u,       // [B,S]
    int* __restrict__ out)                  // [B,S]
{
    const int pos = blockIdx.x;        // b*S + s
    const int tid = threadIdx.x;
    const int lane = tid & 63;
    const int wave = tid >> 6;

    __shared__ unsigned long long sh[NCAND];     // 16 KB, reused as float scratch later
    __shared__ int    s_cand[TOPK];
    __shared__ double s_scores[TOPK];
    __shared__ double s_pd[4], s_ssq[4];

    // ---------------- Phase 1: thread-local top-8 over pred_lm row ----------
    const float* row = pred_lm + (size_t)pos * V;
    unsigned long long loc[TOPK];
    #pragma unroll
    for (int i = 0; i < TOPK; ++i) loc[i] = 0ull;

    // V = 30522 = 2 * 15261 exactly; rows are 8B-aligned every pos -> float2
    const float2* row2 = (const float2*)row;
    constexpr int V2 = V / 2;   // 15261
    for (int i = tid; i < V2; i += BLOCK) {
        float2 f = row2[i];
        unsigned int base = (unsigned int)(i * 2);
        ins8(loc, fkey(f.x, base));
        ins8(loc, fkey(f.y, base + 1));
    }

    #pragma unroll
    for (int j = 0; j < TOPK; ++j) sh[tid * TOPK + j] = loc[j];
    __syncthreads();

    // ---------------- Phase 2: global top-8 from 2048 keys (wave 0) ---------
    for (int it = 0; it < TOPK; ++it) {
        if (tid < 64) {
            unsigned long long m = 0ull;
            int ml = 0;
            for (int j = tid; j < NCAND; j += 64) {
                unsigned long long x = sh[j];
                if (x > m) { m = x; ml = j; }
            }
            #pragma unroll
            for (int off = 32; off; off >>= 1) {
                unsigned long long om = __shfl_down(m, off, 64);
                int ol = __shfl_down(ml, off, 64);
                if (om > m) { m = om; ml = ol; }
            }
            if (tid == 0) {
                s_cand[it] = (int)(~(unsigned int)m);  // low 32 bits hold ~idx
                sh[ml] = 0ull;                         // remove for next round
            }
        }
        __syncthreads();
    }

    // topk_idx *= attention_mask  (mask==0 -> all candidates index 0)
    if (tid == 0 && attn[pos] == 0) {
        #pragma unroll
        for (int k = 0; k < TOPK; ++k) s_cand[k] = 0;
    }
    __syncthreads();

    // ---------------- Phase 3: stage dg/se in LDS + prev_dot/src_sq ---------
    float* shf = (float*)sh;  // reuse: [0..D) = delta_grad row, [D..2D) = src_embeds row
    const float* dg = delta_grad + (size_t)pos * D;
    const float* se = src_embeds + (size_t)pos * D;

    double pd = 0.0, ssq = 0.0;
    for (int i = tid; i < D; i += BLOCK) {
        float g = dg[i], e = se[i];
        shf[i] = g;
        shf[D + i] = e;
        pd  += (double)g * (double)e;
        ssq += (double)e * (double)e;
    }
    #pragma unroll
    for (int off = 32; off; off >>= 1) {
        pd  += __shfl_down(pd, off, 64);
        ssq += __shfl_down(ssq, off, 64);
    }
    if (lane == 0) { s_pd[wave] = pd; s_ssq[wave] = ssq; }
    __syncthreads();

    const double prev_dot = s_pd[0] + s_pd[1] + s_pd[2] + s_pd[3];
    const double src_sq   = s_ssq[0] + s_ssq[1] + s_ssq[2] + s_ssq[3];

    // ---------------- Phase 4: score 8 candidates (2 per wave, fp64) --------
    #pragma unroll
    for (int kk = 0; kk < 2; ++kk) {
        const int k = 2 * wave + kk;
        const int v = s_cand[k];
        const float* ev = emb + (size_t)v * D;
        double ddg = 0.0, dse = 0.0, dvv = 0.0;
        for (int i = lane; i < D; i += 64) {
            double e = (double)ev[i];
            ddg += e * (double)shf[i];
            dse += e * (double)shf[D + i];
            dvv += e * e;
        }
        #pragma unroll
        for (int off = 32; off; off >>= 1) {
            ddg += __shfl_down(ddg, off, 64);
            dse += __shfl_down(dse, off, 64);
            dvv += __shfl_down(dvv, off, 64);
        }
        if (lane == 0) {
            double sq = src_sq + dvv - 2.0 * dse;
            if (sq < 0.0) sq = 0.0;
            double dn = sqrt(sq + 1e-20);
            s_scores[k] = (ddg - prev_dot) / dn;   // dir_dot_grad / dir_norm
        }
    }
    __syncthreads();

    // ---------------- Phase 5: filtered argmax + swap blend (thread 0) ------
    if (tid == 0) {
        const int src_tok = src_tokens[pos];
        int best = 0;
        double best_s = 0.0;
        bool found = false;
        #pragma unroll
        for (int k = 0; k < TOPK; ++k) {
            const int v = s_cand[k];
            if (v < NUM_SPECIAL || v == src_tok) continue;   // -inf in reference
            const double sc = s_scores[k];
            // jnp.argmax: lowest index wins ties
            if (!found || sc > best_s || (sc == best_s && v < best)) {
                best = v; best_s = sc; found = true;
            }
        }
        const int adv_flip = found ? best : 0;   // argmax of all -inf -> 0
        const bool no_special = (src_tok >= NUM_SPECIAL);
        const bool swap = (rand_u[pos] > 0.7f);  // 1.0 - SWAP_RATIO in f32
        out[pos] = (no_special && swap) ? adv_flip : src_tok;
    }
}

extern "C" void kernel_launch(void* const* d_in, const int* in_sizes, int n_in,
                              void* d_out, int out_size, void* d_ws, size_t ws_size,
                              hipStream_t stream) {
    const float* delta_grad = (const float*)d_in[0];
    const float* src_embeds = (const float*)d_in[1];
    const float* emb        = (const float*)d_in[2];
    const int*   src_tokens = (const int*)d_in[3];
    const float* pred_lm    = (const float*)d_in[4];
    const int*   attn       = (const int*)d_in[5];
    const float* randu      = (const float*)d_in[6];
    int* out = (int*)d_out;

    const int BS = in_sizes[3];   // B*S = 2048 positions
    dvat_kernel<<<BS, BLOCK, 0, stream>>>(delta_grad, src_embeds, emb,
                                          src_tokens, pred_lm, attn, randu, out);
}